// Round 8
// baseline (107.311 us; speedup 1.0000x reference)
//
#include <hip/hip_runtime.h>
#include <hip/hip_bf16.h>

#define B_ 2
#define H_ 4
#define BH_ 8
#define T_ 2048
#define D_ 63
#define NS_ 21
#define DP_ 64
#define M_EXP2 12.0f

typedef __attribute__((ext_vector_type(4))) float f32x4;
typedef __attribute__((ext_vector_type(8))) short short8;
typedef __attribute__((ext_vector_type(4))) short short4_t;

// log2(e) / sqrt(63)  (folded into Q during prep)
#define SSCALE 0.18176249f

static __device__ __forceinline__ short f2bf(float f) {
    union { float f; unsigned u; } c; c.f = f;
    unsigned r = c.u + 0x7FFFu + ((c.u >> 16) & 1u);
    return (short)(r >> 16);
}

// ---------------------------------------------------------------------------
// Rotate q,k by quaternion Lie-algebra RoPE -> bf16, padded to 64, Q pre-scaled
// by log2(e)/sqrt(D). 256 thr = 4 waves; each wave owns one (b,t).
// ---------------------------------------------------------------------------
__global__ __launch_bounds__(256) void geope_rotate(
    const float* __restrict__ q, const float* __restrict__ kk,
    const float* __restrict__ coords,
    short* __restrict__ qr, short* __restrict__ kr)
{
    const int sub = threadIdx.x >> 6;
    const int tid = threadIdx.x & 63;
    const int bt = blockIdx.x * 4 + sub;
    const int b = bt / T_;
    const int t = bt - b * T_;

    __shared__ float sIn[4][8][64];        // [wave][4 heads x {q,k}][d]
    __shared__ float sw[4][24], sx[4][24], sy[4][24], sz[4][24];
    __shared__ short sOut[4][8][64];

    for (int idx = tid; idx < 8 * D_; idx += 64) {
        const int row = idx / D_;
        const int col = idx - row * D_;
        const int h = row >> 1;
        const float* src = (row & 1) ? kk : q;
        sIn[sub][row][col] = src[((size_t)((b*H_ + h)*T_) + t)*D_ + col];
    }
    if (tid < NS_) {
        const float cx = coords[(size_t)(b*T_ + t)*3 + 0] * 1e-4f;
        const float cy = coords[(size_t)(b*T_ + t)*3 + 1] * 1e-4f;
        const float cz = coords[(size_t)(b*T_ + t)*3 + 2] * 1e-4f;
        const float invf = exp2f(-5.0f * (float)tid / 21.0f);  // 32^(-s/21)
        const float tx = cx*invf, ty = cy*invf, tz = cz*invf;
        const float Theta = (1.0f/3.0f)*sqrtf(tx*tx + ty*ty + tz*tz + 1e-8f);
        const float hf = 0.5f*Theta;
        const float s = sinf(hf)/(3.0f*Theta + 1e-8f);
        sw[sub][tid] = cosf(hf);
        sx[sub][tid] = s*tx; sy[sub][tid] = s*ty; sz[sub][tid] = s*tz;
    }
    if (tid < 8) sOut[sub][tid][63] = 0;   // zero pad column (q,k pad must be 0)

    for (int task = tid; task < 8*NS_; task += 64) {
        const int row = task / NS_;
        const int s   = task - row*NS_;
        const float vx = sIn[sub][row][s*3+0], vy = sIn[sub][row][s*3+1], vz = sIn[sub][row][s*3+2];
        const float w = sw[sub][s], qx = sx[sub][s], qy = sy[sub][s], qz = sz[sub][s];
        const float t0 = qy*vz - qz*vy;
        const float t1 = qz*vx - qx*vz;
        const float t2 = qx*vy - qy*vx;
        const float px = vx + 2.0f*w*t0 + 2.0f*(qy*t2 - qz*t1);
        const float py = vy + 2.0f*w*t1 + 2.0f*(qz*t0 - qx*t2);
        const float pz = vz + 2.0f*w*t2 + 2.0f*(qx*t1 - qy*t0);
        const float mult = (row & 1) ? 1.0f : SSCALE;   // scale only Q
        sOut[sub][row][s*3+0] = f2bf(px*mult);
        sOut[sub][row][s*3+1] = f2bf(py*mult);
        sOut[sub][row][s*3+2] = f2bf(pz*mult);
    }

    {   // coalesced store: 8 rows x 64 shorts; each lane one short8
        const int row = tid >> 3;
        const int off = (tid & 7) * 8;
        const int h = row >> 1;
        short* dst = (row & 1) ? kr : qr;
        *(short8*)(dst + ((size_t)((b*H_ + h)*T_) + t)*DP_ + off) = *(short8*)&sOut[sub][row][off];
    }
}

// ---------------------------------------------------------------------------
// Tiled V transpose + bf16 cast: vt[bh][d(64)][t]. Pad row d=63 is set to 1.0
// so that O[q][63] = sum_k P[q][k]  (softmax denominator for free via MFMA).
// ---------------------------------------------------------------------------
__global__ __launch_bounds__(256) void geope_vtrans(
    const float* __restrict__ v, short* __restrict__ vt)
{
    const int blk = blockIdx.x;          // bh*(T/64) + ttile
    const int bh = blk >> 5;
    const int t0 = (blk & 31) * 64;
    const int tid = threadIdx.x;
    __shared__ short tile[64][65];

    for (int idx = tid; idx < 64*64; idx += 256) {
        const int tt = idx >> 6;
        const int d  = idx & 63;
        const float val = (d < D_) ? v[((size_t)bh*T_ + t0 + tt)*D_ + d] : 1.0f;
        tile[tt][d] = f2bf(val);
    }
    __syncthreads();

    const int d  = tid >> 2;
    const int tq = (tid & 3) * 16;
    short8 o0, o1;
    #pragma unroll
    for (int i = 0; i < 8; ++i) o0[i] = tile[tq + i][d];
    #pragma unroll
    for (int i = 0; i < 8; ++i) o1[i] = tile[tq + 8 + i][d];
    short* dst = vt + ((size_t)bh*DP_ + d)*T_ + t0 + tq;
    *(short8*)(dst)     = o0;
    *(short8*)(dst + 8) = o1;
}

// ---------------------------------------------------------------------------
// Flash attention over a KV segment, fixed-max softmax, LDS-staged K/V.
// Block = 4 waves x 32 q rows = 128 q; KV tile = 64 keys, double-buffered via
// global_load_lds (linear dest, source pre-swizzled, reads swizzled: chunk^row&7).
// One __syncthreads per iter; next-tile stage issued after the barrier so the
// loads fly during compute. P = exp2(S-12) bf16; denom = PV output at d=63.
// ---------------------------------------------------------------------------
template<int NSPLIT>
__global__ __launch_bounds__(256, 3) void geope_attn_t(
    const short* __restrict__ qr, const short* __restrict__ kr,
    const short* __restrict__ vt, float* __restrict__ out,
    float* __restrict__ opart)
{
    constexpr int SEG = T_ / NSPLIT;
    constexpr int NIT = SEG / 64;
    const int nqt = T_ / 128;
    const int blk = blockIdx.x;
    const int seg = blockIdx.y;
    const int bh = blk / nqt;
    const int q0 = (blk - bh*nqt) * 128;
    const int wave = threadIdx.x >> 6;
    const int lane = threadIdx.x & 63;
    const int r = lane & 15;
    const int g = lane >> 4;
    const int qw = q0 + wave*32;

    __shared__ short kbuf[2][64*64];       // [buf][key(64) x d(64)], rows 128B
    __shared__ short vbuf[2][64*64];       // [buf][d(64) x key(64)], rows 128B
    __shared__ short pbuf[8][16*64];       // [wave*2+u][q(16) x key(64)]

    const short* Qb = qr + (size_t)bh*T_*DP_;
    const short* Kb = kr + (size_t)bh*T_*DP_;
    const short* Vb = vt + (size_t)bh*DP_*T_;

    // Q fragments in regs: q rows qw+u*16+r, k-chunks hh*32+g*8
    short8 qf[2][2];
    #pragma unroll
    for (int u = 0; u < 2; ++u)
        #pragma unroll
        for (int hh = 0; hh < 2; ++hh)
            qf[u][hh] = *(const short8*)(Qb + (size_t)(qw + u*16 + r)*DP_ + hh*32 + g*8);

    const int kbeg = seg * SEG;

    // stage tile k0 into buf: linear LDS dest, swizzled global source
    auto stage = [&](int buf, int k0) {
        #pragma unroll
        for (int s = 0; s < 2; ++s) {
            const int C   = (wave*2 + s) * 1024;          // byte offset in tile
            const int row = (C + lane*16) >> 7;           // 0..63
            const int cs  = (lane & 7) ^ (row & 7);       // swizzled 16B chunk
            const char* gk = (const char*)Kb + (size_t)(k0 + row)*128 + cs*16;
            const char* gv = (const char*)Vb + (size_t)row*4096 + (size_t)k0*2 + cs*16;
            __builtin_amdgcn_global_load_lds(gk, (char*)&kbuf[buf][0] + C, 16, 0, 0);
            __builtin_amdgcn_global_load_lds(gv, (char*)&vbuf[buf][0] + C, 16, 0, 0);
        }
    };

    f32x4 oacc[2][4] = {};                 // [u][dt]: O[q=g*4+j][d=dt*16+r]
    stage(0, kbeg);

    for (int it = 0; it < NIT; ++it) {
        const int buf = it & 1;
        __syncthreads();                   // drains vmcnt: buf ready; WAR-safe
        if (it + 1 < NIT) stage(buf ^ 1, kbeg + (it+1)*64);

        // K fragments from LDS (swizzled read)
        short8 kf[4][2];
        #pragma unroll
        for (int kt = 0; kt < 4; ++kt)
            #pragma unroll
            for (int hh = 0; hh < 2; ++hh) {
                const int row = kt*16 + r;
                kf[kt][hh] = *(const short8*)&kbuf[buf][row*64 + (((hh*4+g)^(r&7))*8)];
            }

        // S^T = K @ Q^T  (D: row=key g*4+j within kt, col=q r), exp2 domain
        f32x4 st[2][4] = {};
        #pragma unroll
        for (int u = 0; u < 2; ++u)
            #pragma unroll
            for (int kt = 0; kt < 4; ++kt) {
                st[u][kt] = __builtin_amdgcn_mfma_f32_16x16x32_bf16(kf[kt][0], qf[u][0], st[u][kt], 0, 0, 0);
                st[u][kt] = __builtin_amdgcn_mfma_f32_16x16x32_bf16(kf[kt][1], qf[u][1], st[u][kt], 0, 0, 0);
            }

        // P = exp2(S - M), pack bf16, write to per-(wave,u) P buffer (swizzled)
        #pragma unroll
        for (int u = 0; u < 2; ++u)
            #pragma unroll
            for (int kt = 0; kt < 4; ++kt) {
                short4_t pk;
                pk[0] = f2bf(exp2f(st[u][kt][0] - M_EXP2));
                pk[1] = f2bf(exp2f(st[u][kt][1] - M_EXP2));
                pk[2] = f2bf(exp2f(st[u][kt][2] - M_EXP2));
                pk[3] = f2bf(exp2f(st[u][kt][3] - M_EXP2));
                const int c16 = (kt*2 + (g>>1)) ^ (r&7);
                *(short4_t*)&pbuf[(wave<<1)+u][r*64 + c16*8 + (g&1)*4] = pk;
            }

        // V + P fragments, O += P @ V  (in-wave LDS RAW via lgkmcnt)
        short8 vf[4][2];
        #pragma unroll
        for (int dt = 0; dt < 4; ++dt)
            #pragma unroll
            for (int hh = 0; hh < 2; ++hh) {
                const int row = dt*16 + r;
                vf[dt][hh] = *(const short8*)&vbuf[buf][row*64 + (((hh*4+g)^(r&7))*8)];
            }
        short8 pa[2][2];
        #pragma unroll
        for (int u = 0; u < 2; ++u)
            #pragma unroll
            for (int hh = 0; hh < 2; ++hh)
                pa[u][hh] = *(const short8*)&pbuf[(wave<<1)+u][r*64 + (((hh*4+g)^(r&7))*8)];
        #pragma unroll
        for (int u = 0; u < 2; ++u)
            #pragma unroll
            for (int dt = 0; dt < 4; ++dt) {
                oacc[u][dt] = __builtin_amdgcn_mfma_f32_16x16x32_bf16(pa[u][0], vf[dt][0], oacc[u][dt], 0, 0, 0);
                oacc[u][dt] = __builtin_amdgcn_mfma_f32_16x16x32_bf16(pa[u][1], vf[dt][1], oacc[u][dt], 0, 0, 0);
            }
    }

    if constexpr (NSPLIT == 1) {
        #pragma unroll
        for (int u = 0; u < 2; ++u)
            #pragma unroll
            for (int j = 0; j < 4; ++j) {
                const float linv = 1.0f / __shfl(oacc[u][3][j], g*16 + 15);
                float* orow = out + ((size_t)bh*T_ + (qw + u*16 + g*4 + j))*D_;
                #pragma unroll
                for (int dt = 0; dt < 4; ++dt) {
                    const int d = dt*16 + r;
                    if (d < D_) orow[d] = oacc[u][dt][j] * linv;
                }
            }
    } else {
        float* op = opart + ((size_t)seg*BH_*T_ + (size_t)bh*T_)*DP_;
        #pragma unroll
        for (int u = 0; u < 2; ++u)
            #pragma unroll
            for (int j = 0; j < 4; ++j) {
                float* orow = op + (size_t)(qw + u*16 + g*4 + j)*DP_;
                #pragma unroll
                for (int dt = 0; dt < 4; ++dt) orow[dt*16 + r] = oacc[u][dt][j];
            }
    }
}

// ---------------------------------------------------------------------------
// Combine KV-split partials: plain sums (fixed-max), denom = column d=63.
// ---------------------------------------------------------------------------
template<int NSPLIT>
__global__ __launch_bounds__(256) void geope_combine(
    const float* __restrict__ opart, float* __restrict__ out)
{
    const int row = blockIdx.x*4 + (threadIdx.x >> 6);
    const int d   = threadIdx.x & 63;
    float o = 0.0f;
    #pragma unroll
    for (int s = 0; s < NSPLIT; ++s)
        o += opart[((size_t)s*BH_*T_ + row)*DP_ + d];
    const float L = __shfl(o, 63);
    if (d < D_) out[(size_t)row*D_ + d] = o / L;
}

extern "C" void kernel_launch(void* const* d_in, const int* in_sizes, int n_in,
                              void* d_out, int out_size, void* d_ws, size_t ws_size,
                              hipStream_t stream)
{
    const float* q      = (const float*)d_in[0];
    const float* k      = (const float*)d_in[1];
    const float* v      = (const float*)d_in[2];
    const float* coords = (const float*)d_in[3];
    float* out = (float*)d_out;

    const size_t NQK = (size_t)B_*H_*T_*DP_;          // elements per bf16 buf
    short* qr = (short*)d_ws;
    short* kr = qr + NQK;
    short* vt = kr + NQK;
    float* opart = (float*)(vt + NQK);
    const size_t base = 3*NQK*sizeof(short);
    const size_t per_seg = (size_t)BH_*T_*DP_*sizeof(float);

    geope_rotate<<<dim3(B_*T_/4), dim3(256), 0, stream>>>(q, k, coords, qr, kr);
    geope_vtrans<<<dim3(BH_*32), dim3(256), 0, stream>>>(v, vt);

    if (ws_size >= base + 8*per_seg) {
        geope_attn_t<8><<<dim3(BH_*16, 8), dim3(256), 0, stream>>>(qr, kr, vt, nullptr, opart);
        geope_combine<8><<<dim3(BH_*T_/4), dim3(256), 0, stream>>>(opart, out);
    } else if (ws_size >= base + 4*per_seg) {
        geope_attn_t<4><<<dim3(BH_*16, 4), dim3(256), 0, stream>>>(qr, kr, vt, nullptr, opart);
        geope_combine<4><<<dim3(BH_*T_/4), dim3(256), 0, stream>>>(opart, out);
    } else {
        geope_attn_t<1><<<dim3(BH_*16, 1), dim3(256), 0, stream>>>(qr, kr, vt, out, nullptr);
    }
}

// Round 11
// 100.234 us; speedup vs baseline: 1.0706x; 1.0706x over previous
//
#include <hip/hip_runtime.h>
#include <hip/hip_bf16.h>

#define B_ 2
#define H_ 4
#define BH_ 8
#define T_ 2048
#define D_ 63
#define NS_ 21
#define DP_ 64
#define M_EXP2 12.0f

typedef __attribute__((ext_vector_type(4))) float f32x4;
typedef __attribute__((ext_vector_type(8))) short short8;
typedef __attribute__((ext_vector_type(4))) short short4_t;

// log2(e) / sqrt(63)  (folded into Q during prep)
#define SSCALE 0.18176249f

static __device__ __forceinline__ short f2bf(float f) {
    union { float f; unsigned u; } c; c.f = f;
    unsigned r = c.u + 0x7FFFu + ((c.u >> 16) & 1u);
    return (short)(r >> 16);
}

// ---------------------------------------------------------------------------
// Fused prep. Blocks [0, B*T/4): quaternion RoPE rotate of q,k -> bf16 padded
// to 64, Q pre-scaled by log2(e)/sqrt(D); one wave per (b,t), wave-synchronous.
// Blocks [B*T/4, +BH*32): tiled V transpose -> vt[bh][d(64)][t], pad row
// d=63 = 1.0 so O[q][63] = sum_k P[q][k] (softmax denominator via MFMA).
// ---------------------------------------------------------------------------
__global__ __launch_bounds__(256) void geope_prep(
    const float* __restrict__ q, const float* __restrict__ kk,
    const float* __restrict__ v, const float* __restrict__ coords,
    short* __restrict__ qr, short* __restrict__ kr, short* __restrict__ vt)
{
    __shared__ float sIn[4][8][64];        // [wave][4 heads x {q,k}][d]
    __shared__ float sw[4][24], sx[4][24], sy[4][24], sz[4][24];
    __shared__ short sOut[4][8][64];
    __shared__ short tile[64][65];

    if (blockIdx.x < B_*T_/4) {
        // ---------------- rotate part (wave-synchronous, 1 wave = 1 (b,t)) --
        const int sub = threadIdx.x >> 6;
        const int tid = threadIdx.x & 63;
        const int bt = blockIdx.x * 4 + sub;
        const int b = bt / T_;
        const int t = bt - b * T_;

        for (int idx = tid; idx < 8 * D_; idx += 64) {
            const int row = idx / D_;
            const int col = idx - row * D_;
            const int h = row >> 1;
            const float* src = (row & 1) ? kk : q;
            sIn[sub][row][col] = src[((size_t)((b*H_ + h)*T_) + t)*D_ + col];
        }
        if (tid < NS_) {
            const float cx = coords[(size_t)(b*T_ + t)*3 + 0] * 1e-4f;
            const float cy = coords[(size_t)(b*T_ + t)*3 + 1] * 1e-4f;
            const float cz = coords[(size_t)(b*T_ + t)*3 + 2] * 1e-4f;
            const float invf = exp2f(-5.0f * (float)tid / 21.0f);  // 32^(-s/21)
            const float tx = cx*invf, ty = cy*invf, tz = cz*invf;
            const float Theta = (1.0f/3.0f)*sqrtf(tx*tx + ty*ty + tz*tz + 1e-8f);
            const float hf = 0.5f*Theta;
            const float s = sinf(hf)/(3.0f*Theta + 1e-8f);
            sw[sub][tid] = cosf(hf);
            sx[sub][tid] = s*tx; sy[sub][tid] = s*ty; sz[sub][tid] = s*tz;
        }
        if (tid < 8) sOut[sub][tid][63] = 0;   // zero pad col (q,k pad must be 0)

        for (int task = tid; task < 8*NS_; task += 64) {
            const int row = task / NS_;
            const int s   = task - row*NS_;
            const float vx = sIn[sub][row][s*3+0], vy = sIn[sub][row][s*3+1], vz = sIn[sub][row][s*3+2];
            const float w = sw[sub][s], qx = sx[sub][s], qy = sy[sub][s], qz = sz[sub][s];
            const float t0 = qy*vz - qz*vy;
            const float t1 = qz*vx - qx*vz;
            const float t2 = qx*vy - qy*vx;
            const float px = vx + 2.0f*w*t0 + 2.0f*(qy*t2 - qz*t1);
            const float py = vy + 2.0f*w*t1 + 2.0f*(qz*t0 - qx*t2);
            const float pz = vz + 2.0f*w*t2 + 2.0f*(qx*t1 - qy*t0);
            const float mult = (row & 1) ? 1.0f : SSCALE;   // scale only Q
            sOut[sub][row][s*3+0] = f2bf(px*mult);
            sOut[sub][row][s*3+1] = f2bf(py*mult);
            sOut[sub][row][s*3+2] = f2bf(pz*mult);
        }

        {   // coalesced store: 8 rows x 64 shorts; each lane one short8
            const int row = tid >> 3;
            const int off = (tid & 7) * 8;
            const int h = row >> 1;
            short* dst = (row & 1) ? kr : qr;
            *(short8*)(dst + ((size_t)((b*H_ + h)*T_) + t)*DP_ + off) = *(short8*)&sOut[sub][row][off];
        }
    } else {
        // ---------------- V transpose part ---------------------------------
        const int blk = blockIdx.x - B_*T_/4;   // bh*(T/64) + ttile
        const int bh = blk >> 5;
        const int t0 = (blk & 31) * 64;
        const int tid = threadIdx.x;

        for (int idx = tid; idx < 64*64; idx += 256) {
            const int tt = idx >> 6;
            const int d  = idx & 63;
            const float val = (d < D_) ? v[((size_t)bh*T_ + t0 + tt)*D_ + d] : 1.0f;
            tile[tt][d] = f2bf(val);
        }
        __syncthreads();

        const int d  = tid >> 2;
        const int tq = (tid & 3) * 16;
        short8 o0, o1;
        #pragma unroll
        for (int i = 0; i < 8; ++i) o0[i] = tile[tq + i][d];
        #pragma unroll
        for (int i = 0; i < 8; ++i) o1[i] = tile[tq + 8 + i][d];
        short* dst = vt + ((size_t)bh*DP_ + d)*T_ + t0 + tq;
        *(short8*)(dst)     = o0;
        *(short8*)(dst + 8) = o1;
    }
}

// ---------------------------------------------------------------------------
// Flash attention over a KV segment, fixed-max softmax, LDS-staged K/V.
// Block = 4 waves x 32 q rows = 128 q; KV tile = 64 keys, double-buffered via
// global_load_lds (linear dest, source pre-swizzled, reads swizzled: chunk^row&7).
// One __syncthreads per iter; next-tile stage issued after the barrier so the
// loads fly during compute. P = exp2(S-12) bf16 (f2bf pack, R8-proven);
// denom = PV output at d=63.
// ---------------------------------------------------------------------------
template<int NSPLIT>
__global__ __launch_bounds__(256, 3) void geope_attn_t(
    const short* __restrict__ qr, const short* __restrict__ kr,
    const short* __restrict__ vt, float* __restrict__ out,
    float* __restrict__ opart)
{
    constexpr int SEG = T_ / NSPLIT;
    constexpr int NIT = SEG / 64;
    const int nqt = T_ / 128;
    const int blk = blockIdx.x;
    const int seg = blockIdx.y;
    const int bh = blk / nqt;
    const int q0 = (blk - bh*nqt) * 128;
    const int wave = threadIdx.x >> 6;
    const int lane = threadIdx.x & 63;
    const int r = lane & 15;
    const int g = lane >> 4;
    const int qw = q0 + wave*32;

    __shared__ short kbuf[2][64*64];       // [buf][key(64) x d(64)], rows 128B
    __shared__ short vbuf[2][64*64];       // [buf][d(64) x key(64)], rows 128B
    __shared__ short pbuf[8][16*64];       // [wave*2+u][q(16) x key(64)]

    const short* Qb = qr + (size_t)bh*T_*DP_;
    const short* Kb = kr + (size_t)bh*T_*DP_;
    const short* Vb = vt + (size_t)bh*DP_*T_;

    // Q fragments in regs: q rows qw+u*16+r, k-chunks hh*32+g*8
    short8 qf[2][2];
    #pragma unroll
    for (int u = 0; u < 2; ++u)
        #pragma unroll
        for (int hh = 0; hh < 2; ++hh)
            qf[u][hh] = *(const short8*)(Qb + (size_t)(qw + u*16 + r)*DP_ + hh*32 + g*8);

    const int kbeg = seg * SEG;

    // stage tile k0 into buf: linear LDS dest, swizzled global source
    auto stage = [&](int buf, int k0) {
        #pragma unroll
        for (int s = 0; s < 2; ++s) {
            const int C   = (wave*2 + s) * 1024;          // byte offset in tile
            const int row = (C + lane*16) >> 7;           // 0..63
            const int cs  = (lane & 7) ^ (row & 7);       // swizzled 16B chunk
            const char* gk = (const char*)Kb + (size_t)(k0 + row)*128 + cs*16;
            const char* gv = (const char*)Vb + (size_t)row*4096 + (size_t)k0*2 + cs*16;
            __builtin_amdgcn_global_load_lds(gk, (char*)&kbuf[buf][0] + C, 16, 0, 0);
            __builtin_amdgcn_global_load_lds(gv, (char*)&vbuf[buf][0] + C, 16, 0, 0);
        }
    };

    f32x4 oacc[2][4] = {};                 // [u][dt]: O[q=g*4+j][d=dt*16+r]
    stage(0, kbeg);

    for (int it = 0; it < NIT; ++it) {
        const int buf = it & 1;
        __syncthreads();                   // drains vmcnt: buf ready; WAR-safe
        if (it + 1 < NIT) stage(buf ^ 1, kbeg + (it+1)*64);

        // K fragments from LDS (swizzled read)
        short8 kf[4][2];
        #pragma unroll
        for (int kt = 0; kt < 4; ++kt)
            #pragma unroll
            for (int hh = 0; hh < 2; ++hh) {
                const int row = kt*16 + r;
                kf[kt][hh] = *(const short8*)&kbuf[buf][row*64 + (((hh*4+g)^(r&7))*8)];
            }

        // S^T = K @ Q^T  (D: row=key g*4+j within kt, col=q r), exp2 domain
        f32x4 st[2][4] = {};
        #pragma unroll
        for (int u = 0; u < 2; ++u)
            #pragma unroll
            for (int kt = 0; kt < 4; ++kt) {
                st[u][kt] = __builtin_amdgcn_mfma_f32_16x16x32_bf16(kf[kt][0], qf[u][0], st[u][kt], 0, 0, 0);
                st[u][kt] = __builtin_amdgcn_mfma_f32_16x16x32_bf16(kf[kt][1], qf[u][1], st[u][kt], 0, 0, 0);
            }

        // P = exp2(S - M), pack bf16, write to per-(wave,u) P buffer (swizzled)
        #pragma unroll
        for (int u = 0; u < 2; ++u)
            #pragma unroll
            for (int kt = 0; kt < 4; ++kt) {
                short4_t pk;
                pk[0] = f2bf(exp2f(st[u][kt][0] - M_EXP2));
                pk[1] = f2bf(exp2f(st[u][kt][1] - M_EXP2));
                pk[2] = f2bf(exp2f(st[u][kt][2] - M_EXP2));
                pk[3] = f2bf(exp2f(st[u][kt][3] - M_EXP2));
                const int c16 = (kt*2 + (g>>1)) ^ (r&7);
                *(short4_t*)&pbuf[(wave<<1)+u][r*64 + c16*8 + (g&1)*4] = pk;
            }

        // V + P fragments, O += P @ V  (in-wave LDS RAW via lgkmcnt)
        short8 vf[4][2];
        #pragma unroll
        for (int dt = 0; dt < 4; ++dt)
            #pragma unroll
            for (int hh = 0; hh < 2; ++hh) {
                const int row = dt*16 + r;
                vf[dt][hh] = *(const short8*)&vbuf[buf][row*64 + (((hh*4+g)^(r&7))*8)];
            }
        short8 pa[2][2];
        #pragma unroll
        for (int u = 0; u < 2; ++u)
            #pragma unroll
            for (int hh = 0; hh < 2; ++hh)
                pa[u][hh] = *(const short8*)&pbuf[(wave<<1)+u][r*64 + (((hh*4+g)^(r&7))*8)];
        #pragma unroll
        for (int u = 0; u < 2; ++u)
            #pragma unroll
            for (int dt = 0; dt < 4; ++dt) {
                oacc[u][dt] = __builtin_amdgcn_mfma_f32_16x16x32_bf16(pa[u][0], vf[dt][0], oacc[u][dt], 0, 0, 0);
                oacc[u][dt] = __builtin_amdgcn_mfma_f32_16x16x32_bf16(pa[u][1], vf[dt][1], oacc[u][dt], 0, 0, 0);
            }
    }

    if constexpr (NSPLIT == 1) {
        #pragma unroll
        for (int u = 0; u < 2; ++u)
            #pragma unroll
            for (int j = 0; j < 4; ++j) {
                const float linv = 1.0f / __shfl(oacc[u][3][j], g*16 + 15);
                float* orow = out + ((size_t)bh*T_ + (qw + u*16 + g*4 + j))*D_;
                #pragma unroll
                for (int dt = 0; dt < 4; ++dt) {
                    const int d = dt*16 + r;
                    if (d < D_) orow[d] = oacc[u][dt][j] * linv;
                }
            }
    } else {
        float* op = opart + ((size_t)seg*BH_*T_ + (size_t)bh*T_)*DP_;
        #pragma unroll
        for (int u = 0; u < 2; ++u)
            #pragma unroll
            for (int j = 0; j < 4; ++j) {
                float* orow = op + (size_t)(qw + u*16 + g*4 + j)*DP_;
                #pragma unroll
                for (int dt = 0; dt < 4; ++dt) orow[dt*16 + r] = oacc[u][dt][j];
            }
    }
}

// ---------------------------------------------------------------------------
// Combine KV-split partials: plain sums (fixed-max), denom = column d=63.
// One wave per q-row, 4 rows/block.
// ---------------------------------------------------------------------------
template<int NSPLIT>
__global__ __launch_bounds__(256) void geope_combine(
    const float* __restrict__ opart, float* __restrict__ out)
{
    const int row = blockIdx.x*4 + (threadIdx.x >> 6);
    const int d   = threadIdx.x & 63;
    float o = 0.0f;
    #pragma unroll
    for (int s = 0; s < NSPLIT; ++s)
        o += opart[((size_t)s*BH_*T_ + row)*DP_ + d];
    const float L = __shfl(o, 63);
    if (d < D_) out[(size_t)row*D_ + d] = o / L;
}

extern "C" void kernel_launch(void* const* d_in, const int* in_sizes, int n_in,
                              void* d_out, int out_size, void* d_ws, size_t ws_size,
                              hipStream_t stream)
{
    const float* q      = (const float*)d_in[0];
    const float* k      = (const float*)d_in[1];
    const float* v      = (const float*)d_in[2];
    const float* coords = (const float*)d_in[3];
    float* out = (float*)d_out;

    const size_t NQK = (size_t)B_*H_*T_*DP_;          // elements per bf16 buf
    short* qr = (short*)d_ws;
    short* kr = qr + NQK;
    short* vt = kr + NQK;
    float* opart = (float*)(vt + NQK);
    const size_t base = 3*NQK*sizeof(short);
    const size_t per_seg = (size_t)BH_*T_*DP_*sizeof(float);

    geope_prep<<<dim3(B_*T_/4 + BH_*32), dim3(256), 0, stream>>>(q, k, v, coords, qr, kr, vt);

    if (ws_size >= base + 4*per_seg) {
        geope_attn_t<4><<<dim3(BH_*16, 4), dim3(256), 0, stream>>>(qr, kr, vt, nullptr, opart);
        geope_combine<4><<<dim3(BH_*T_/4), dim3(256), 0, stream>>>(opart, out);
    } else if (ws_size >= base + 2*per_seg) {
        geope_attn_t<2><<<dim3(BH_*16, 2), dim3(256), 0, stream>>>(qr, kr, vt, nullptr, opart);
        geope_combine<2><<<dim3(BH_*T_/4), dim3(256), 0, stream>>>(opart, out);
    } else {
        geope_attn_t<1><<<dim3(BH_*16, 1), dim3(256), 0, stream>>>(qr, kr, vt, out, nullptr);
    }
}